// Round 10
// baseline (214.018 us; speedup 1.0000x reference)
//
#include <hip/hip_runtime.h>
#include <hip/hip_bf16.h>
#include <hip/hip_fp16.h>

#define D 128

__device__ __forceinline__ float bf2f(unsigned short u) {
  return __uint_as_float(((unsigned int)u) << 16);
}
__device__ __forceinline__ unsigned short f2bf(float f) {
  unsigned int x = __float_as_uint(f);
  x += 0x7fff + ((x >> 16) & 1);
  return (unsigned short)(x >> 16);
}
__device__ __forceinline__ float h2f(unsigned short b) {
  return __half2float(__ushort_as_half(b));
}
// unpack 2 fp16 packed in a uint
__device__ __forceinline__ float2 up2(unsigned int u) {
  __half2 h = *reinterpret_cast<__half2*>(&u);
  return __half22float2(h);
}
// a[0..7] += w * (8 fp16 packed in uint4)
__device__ __forceinline__ void fma8h(float* a, uint4 v, float w) {
  float2 t;
  t = up2(v.x); a[0] += w * t.x; a[1] += w * t.y;
  t = up2(v.y); a[2] += w * t.x; a[3] += w * t.y;
  t = up2(v.z); a[4] += w * t.x; a[5] += w * t.y;
  t = up2(v.w); a[6] += w * t.x; a[7] += w * t.y;
}
// add 8 bf16 (packed in uint4) into 8 float accumulators
__device__ __forceinline__ void add8(float* a, uint4 v) {
  a[0] += __uint_as_float(v.x << 16);
  a[1] += __uint_as_float(v.x & 0xffff0000u);
  a[2] += __uint_as_float(v.y << 16);
  a[3] += __uint_as_float(v.y & 0xffff0000u);
  a[4] += __uint_as_float(v.z << 16);
  a[5] += __uint_as_float(v.z & 0xffff0000u);
  a[6] += __uint_as_float(v.w << 16);
  a[7] += __uint_as_float(v.w & 0xffff0000u);
}

// flags: [0..4]=float tensor is-bf16 (emb,W1,b1,W2,b2), [5]=ints-int64

// fused: dtype detect (blocks 0..5) + zero indeg (nn ints) + zero P (ngD floats)
__global__ void k_prep(const unsigned short* __restrict__ t0, int n0,
                       const unsigned short* __restrict__ t1, int n1,
                       const unsigned short* __restrict__ t2, int n2,
                       const unsigned short* __restrict__ t3, int n3,
                       const unsigned short* __restrict__ t4, int n4,
                       const unsigned int* __restrict__ ei32,
                       int* __restrict__ flag, int* __restrict__ indeg,
                       float* __restrict__ P, int nn, int ngD) {
  int b = blockIdx.x;
  if (b < 5) {
    const unsigned short* tabs[5] = {t0, t1, t2, t3, t4};
    int ns[5] = {n0, n1, n2, n3, n4};
    const unsigned short* u16 = tabs[b];
    int n = ns[b];
    __shared__ int cnt;
    int K = n / 2 < 256 ? n / 2 : 256;
    if (threadIdx.x == 0) cnt = 0;
    __syncthreads();
    if (threadIdx.x < K) {
      unsigned short u = u16[threadIdx.x * 2];
      int e = (u >> 7) & 0xFF;
      if (u == 0 || (e >= 100 && e <= 140)) atomicAdd(&cnt, 1);
    }
    __syncthreads();
    if (threadIdx.x == 0) flag[b] = (cnt * 2 >= K) ? 1 : 0;
  } else if (b == 5) {
    __shared__ int z;
    if (threadIdx.x == 0) z = 0;
    __syncthreads();
    if (threadIdx.x < 64 && ei32[threadIdx.x * 2 + 1] == 0u) atomicAdd(&z, 1);
    __syncthreads();
    if (threadIdx.x == 0) flag[5] = (z >= 60) ? 1 : 0;
  } else {
    int i = (b - 6) * 256 + threadIdx.x;
    if (i < nn) indeg[i] = 0;
    int j = i - nn;
    if (j >= 0 && j < ngD) P[j] = 0.f;
  }
}

// fused: int conversion (x, batch) + in-degree count from raw edge dst
// (blocks < convBlocks) AND G = emb @ W1 fp16 (remaining blocks).
// srcs/dsts are never materialized — k_fill re-reads edge_index (L3-warm).
__global__ void k_convi_gemm(const void* __restrict__ xr, const void* __restrict__ eir,
                             const void* __restrict__ br,
                             int* __restrict__ xs, int* __restrict__ batchs,
                             int* __restrict__ indeg,
                             int nn, int ne, int vocab, int ng,
                             const int* __restrict__ flag,
                             const void* __restrict__ emb,
                             const void* __restrict__ W1,
                             unsigned short* __restrict__ G,
                             int convBlocks) {
  if (blockIdx.x < convBlocks) {
    long long i = (long long)blockIdx.x * blockDim.x + threadIdx.x;
    int is64 = flag[5];
    if (i < nn) {
      int v = is64 ? (int)((const long long*)xr)[i] : ((const int*)xr)[i];
      v = v < 0 ? 0 : (v > vocab - 1 ? vocab - 1 : v);
      xs[i] = v;
    } else if (i < (long long)nn + ne) {
      long long j = i - nn;
      int v = is64 ? (int)((const long long*)eir)[ne + j] : ((const int*)eir)[ne + j];
      v = v < 0 ? 0 : (v > nn - 1 ? nn - 1 : v);
      atomicAdd(&indeg[v], 1);
    } else if (i < 2LL * nn + ne) {
      long long j = i - nn - ne;
      int v = is64 ? (int)((const long long*)br)[j] : ((const int*)br)[j];
      v = v < 0 ? 0 : (v > ng - 1 ? ng - 1 : v);
      batchs[j] = v;
    }
  } else {
    int idx = (blockIdx.x - convBlocks) * blockDim.x + threadIdx.x;
    if (idx >= vocab * D) return;
    int r = idx >> 7, c = idx & 127;
    int fe = flag[0], fw = flag[1];
    const float* ef = (const float*)emb;
    const unsigned short* eu = (const unsigned short*)emb;
    const float* wf = (const float*)W1;
    const unsigned short* wu = (const unsigned short*)W1;
    size_t ro = (size_t)r * D;
    float acc = 0.f;
    if (fe) {
      if (fw) { for (int k = 0; k < D; ++k) acc += bf2f(eu[ro + k]) * bf2f(wu[k * D + c]); }
      else    { for (int k = 0; k < D; ++k) acc += bf2f(eu[ro + k]) * wf[k * D + c]; }
    } else {
      if (fw) { for (int k = 0; k < D; ++k) acc += ef[ro + k] * bf2f(wu[k * D + c]); }
      else    { for (int k = 0; k < D; ++k) acc += ef[ro + k] * wf[k * D + c]; }
    }
    G[idx] = __half_as_ushort(__float2half_rn(acc));
  }
}

// ---------------- CSR scan -------------------------------------------------
__global__ __launch_bounds__(1024) void k_scan1(const int* __restrict__ indeg,
                                                int* __restrict__ off,
                                                int* __restrict__ bsum, int nn) {
  int t = threadIdx.x;
  int idx = blockIdx.x * 1024 + t;
  int v = (idx < nn) ? indeg[idx] : 0;
  int lane = t & 63, wid = t >> 6;
  int inc = v;
  #pragma unroll
  for (int d = 1; d < 64; d <<= 1) {
    int u = __shfl_up(inc, d);
    if (lane >= d) inc += u;
  }
  __shared__ int ws[16];
  if (lane == 63) ws[wid] = inc;
  __syncthreads();
  if (wid == 0) {
    int wv = (lane < 16) ? ws[lane] : 0;
    #pragma unroll
    for (int d = 1; d < 16; d <<= 1) {
      int u = __shfl_up(wv, d);
      if (lane >= d) wv += u;
    }
    if (lane < 16) ws[lane] = wv;
  }
  __syncthreads();
  int base = wid ? ws[wid - 1] : 0;
  if (idx < nn) off[idx] = base + inc - v;
  if (t == 1023) bsum[blockIdx.x] = ws[15];
}

// fused scan2+scan3: each 1024-block reduces bsum[0..blockIdx-1] itself
__global__ __launch_bounds__(1024) void k_scan23(int* __restrict__ off,
                                                 int* __restrict__ cursor,
                                                 float* __restrict__ dis,
                                                 const int* __restrict__ indeg,
                                                 const int* __restrict__ bsum,
                                                 int nn) {
  int b = blockIdx.x, t = threadIdx.x;
  int v = (t < b) ? bsum[t] : 0;  // nb <= 98 < 1024
  #pragma unroll
  for (int d = 32; d; d >>= 1) v += __shfl_xor(v, d);
  __shared__ int ws[16];
  __shared__ int prefix;
  int lane = t & 63, wid = t >> 6;
  if (lane == 0) ws[wid] = v;
  __syncthreads();
  if (t == 0) {
    int s = 0;
    #pragma unroll
    for (int i = 0; i < 16; ++i) s += ws[i];
    prefix = s;
  }
  __syncthreads();
  int idx = b * 1024 + t;
  if (idx < nn) {
    int o = off[idx] + prefix;
    off[idx] = o;
    cursor[idx] = o;
    dis[idx] = rsqrtf((float)indeg[idx] + 1.0f);  // +1 self-loop
  }
}

// fill unified CSR from RAW edge_index: csr[pp] = { src, x[src]|f16(dis)<<16 }
__global__ void k_fill(const void* __restrict__ eir,
                       const int* __restrict__ xs, const float* __restrict__ dis,
                       int* __restrict__ cursor, int2* __restrict__ csr,
                       int ne, int nn, const int* __restrict__ flag64) {
  int e = blockIdx.x * blockDim.x + threadIdx.x;
  if (e >= ne) return;
  int is64 = *flag64;
  int s, d;
  if (is64) {
    s = (int)((const long long*)eir)[e];
    d = (int)((const long long*)eir)[ne + e];
  } else {
    s = ((const int*)eir)[e];
    d = ((const int*)eir)[ne + e];
  }
  s = s < 0 ? 0 : (s > nn - 1 ? nn - 1 : s);
  d = d < 0 ? 0 : (d > nn - 1 ? nn - 1 : d);
  unsigned short hb = __half_as_ushort(__float2half_rn(dis[s]));
  unsigned int packed = (unsigned int)xs[s] | ((unsigned int)hb << 16);
  int pp = atomicAdd(&cursor[d], 1);
  csr[pp] = make_int2(s, (int)packed);
}

// ---- layer1: H1p[n] = dn * relu(dn*(dn*G[x[n]] + sum dis_s*G[x_s]) + b1) --
// 16 lanes/node; ROW double-buffer (same structure that won in agg2pool):
// load batch k+1's rows + weights while fma-ing batch k.
__global__ __launch_bounds__(256) void k_aggrelu(const int* __restrict__ x,
                                                 const unsigned short* __restrict__ G,
                                                 const void* __restrict__ b1,
                                                 const int* __restrict__ off,
                                                 const int* __restrict__ indeg,
                                                 const float* __restrict__ dis,
                                                 const int2* __restrict__ csr,
                                                 unsigned short* __restrict__ H1,
                                                 int nn, const int* __restrict__ flag) {
  int gid = blockIdx.x * blockDim.x + threadIdx.x;
  int n = gid >> 4;
  if (n >= nn) return;
  int lane = threadIdx.x & 15;
  float dn = dis[n];
  const uint4* G4 = (const uint4*)G;  // fp16 row = 16 uint4 (256 B)
  float a[8];
  {
    uint4 v = G4[(size_t)x[n] * 16 + lane];
    float2 t;
    t = up2(v.x); a[0] = dn * t.x; a[1] = dn * t.y;
    t = up2(v.y); a[2] = dn * t.x; a[3] = dn * t.y;
    t = up2(v.z); a[4] = dn * t.x; a[5] = dn * t.y;
    t = up2(v.w); a[6] = dn * t.x; a[7] = dn * t.y;
  }
  int s0 = off[n], m = indeg[n];
  int j = 0;
  if (m >= 4) {
    unsigned c0 = (unsigned)csr[s0].y,     c1 = (unsigned)csr[s0 + 1].y;
    unsigned c2 = (unsigned)csr[s0 + 2].y, c3 = (unsigned)csr[s0 + 3].y;
    uint4 vA = G4[(size_t)(c0 & 0xFFFFu) * 16 + lane];
    uint4 vB = G4[(size_t)(c1 & 0xFFFFu) * 16 + lane];
    uint4 vC = G4[(size_t)(c2 & 0xFFFFu) * 16 + lane];
    uint4 vD = G4[(size_t)(c3 & 0xFFFFu) * 16 + lane];
    float w0 = h2f((unsigned short)(c0 >> 16));
    float w1 = h2f((unsigned short)(c1 >> 16));
    float w2 = h2f((unsigned short)(c2 >> 16));
    float w3 = h2f((unsigned short)(c3 >> 16));
    for (; j + 8 <= m; j += 4) {
      unsigned p0 = (unsigned)csr[s0 + j + 4].y, p1 = (unsigned)csr[s0 + j + 5].y;
      unsigned p2 = (unsigned)csr[s0 + j + 6].y, p3 = (unsigned)csr[s0 + j + 7].y;
      uint4 wA = G4[(size_t)(p0 & 0xFFFFu) * 16 + lane];
      uint4 wB = G4[(size_t)(p1 & 0xFFFFu) * 16 + lane];
      uint4 wC = G4[(size_t)(p2 & 0xFFFFu) * 16 + lane];
      uint4 wD = G4[(size_t)(p3 & 0xFFFFu) * 16 + lane];
      fma8h(a, vA, w0); fma8h(a, vB, w1); fma8h(a, vC, w2); fma8h(a, vD, w3);
      vA = wA; vB = wB; vC = wC; vD = wD;
      w0 = h2f((unsigned short)(p0 >> 16));
      w1 = h2f((unsigned short)(p1 >> 16));
      w2 = h2f((unsigned short)(p2 >> 16));
      w3 = h2f((unsigned short)(p3 >> 16));
    }
    fma8h(a, vA, w0); fma8h(a, vB, w1); fma8h(a, vC, w2); fma8h(a, vD, w3);
    j += 4;
  }
  for (; j < m; ++j) {
    unsigned c = (unsigned)csr[s0 + j].y;
    uint4 v = G4[(size_t)(c & 0xFFFFu) * 16 + lane];
    fma8h(a, v, h2f((unsigned short)(c >> 16)));
  }
  float bb[8];
  if (flag[2]) {
    uint4 bu = ((const uint4*)b1)[lane];  // 8 bf16
    bb[0] = bf2f((unsigned short)(bu.x & 0xFFFF)); bb[1] = bf2f((unsigned short)(bu.x >> 16));
    bb[2] = bf2f((unsigned short)(bu.y & 0xFFFF)); bb[3] = bf2f((unsigned short)(bu.y >> 16));
    bb[4] = bf2f((unsigned short)(bu.z & 0xFFFF)); bb[5] = bf2f((unsigned short)(bu.z >> 16));
    bb[6] = bf2f((unsigned short)(bu.w & 0xFFFF)); bb[7] = bf2f((unsigned short)(bu.w >> 16));
  } else {
    float4 b0 = ((const float4*)b1)[2 * lane];
    float4 b1v = ((const float4*)b1)[2 * lane + 1];
    bb[0] = b0.x; bb[1] = b0.y; bb[2] = b0.z; bb[3] = b0.w;
    bb[4] = b1v.x; bb[5] = b1v.y; bb[6] = b1v.z; bb[7] = b1v.w;
  }
  ushort4 o0, o1;
  o0.x = f2bf(dn * fmaxf(dn * a[0] + bb[0], 0.f));
  o0.y = f2bf(dn * fmaxf(dn * a[1] + bb[1], 0.f));
  o0.z = f2bf(dn * fmaxf(dn * a[2] + bb[2], 0.f));
  o0.w = f2bf(dn * fmaxf(dn * a[3] + bb[3], 0.f));
  o1.x = f2bf(dn * fmaxf(dn * a[4] + bb[4], 0.f));
  o1.y = f2bf(dn * fmaxf(dn * a[5] + bb[5], 0.f));
  o1.z = f2bf(dn * fmaxf(dn * a[6] + bb[6], 0.f));
  o1.w = f2bf(dn * fmaxf(dn * a[7] + bb[7], 0.f));
  ((ushort4*)(H1 + (size_t)n * D))[2 * lane] = o0;
  ((ushort4*)(H1 + (size_t)n * D))[2 * lane + 1] = o1;
}

// ---- fused layer2 + pool: 16 lanes/node, uint4 (16B) loads; ROW double-
// buffer: chunk k+1's 4 row-loads issued before consuming chunk k, so add8
// VALU overlaps load flight (explicit scalars, no predication).
__global__ __launch_bounds__(256) void k_agg2pool(
    const unsigned short* __restrict__ H1, const int* __restrict__ off,
    const int* __restrict__ indeg, const float* __restrict__ dis,
    const int2* __restrict__ csr, const int* __restrict__ batch,
    float* __restrict__ P, int nn) {
  __shared__ float buf[16][D];
  __shared__ int gbuf[16];
  int t = threadIdx.x;
  int slot = t >> 4, lane = t & 15;
  int n = blockIdx.x * 16 + slot;
  float a[8] = {0.f, 0.f, 0.f, 0.f, 0.f, 0.f, 0.f, 0.f};
  if (n < nn) {
    float dn = dis[n];
    const uint4* H4 = (const uint4*)H1;  // row = 16 uint4
    add8(a, H4[(size_t)n * 16 + lane]);  // self term
    int s0 = off[n], m = indeg[n];
    int j = 0;
    if (m >= 4) {
      int i0 = csr[s0].x, i1 = csr[s0 + 1].x;
      int i2 = csr[s0 + 2].x, i3 = csr[s0 + 3].x;
      uint4 vA = H4[(size_t)i0 * 16 + lane];
      uint4 vB = H4[(size_t)i1 * 16 + lane];
      uint4 vC = H4[(size_t)i2 * 16 + lane];
      uint4 vD = H4[(size_t)i3 * 16 + lane];
      for (; j + 8 <= m; j += 4) {
        int p0 = csr[s0 + j + 4].x, p1 = csr[s0 + j + 5].x;
        int p2 = csr[s0 + j + 6].x, p3 = csr[s0 + j + 7].x;
        uint4 wA = H4[(size_t)p0 * 16 + lane];
        uint4 wB = H4[(size_t)p1 * 16 + lane];
        uint4 wC = H4[(size_t)p2 * 16 + lane];
        uint4 wD = H4[(size_t)p3 * 16 + lane];
        add8(a, vA); add8(a, vB); add8(a, vC); add8(a, vD);
        vA = wA; vB = wB; vC = wC; vD = wD;
      }
      add8(a, vA); add8(a, vB); add8(a, vC); add8(a, vD);
      j += 4;
    }
    for (; j < m; ++j) {
      int e = csr[s0 + j].x;
      add8(a, H4[(size_t)e * 16 + lane]);
    }
    #pragma unroll
    for (int q = 0; q < 8; ++q) a[q] *= dn;
  }
  ((float4*)&buf[slot][lane * 8])[0] = make_float4(a[0], a[1], a[2], a[3]);
  ((float4*)&buf[slot][lane * 8])[1] = make_float4(a[4], a[5], a[6], a[7]);
  if (lane == 0) gbuf[slot] = (n < nn) ? batch[n] : -1;
  __syncthreads();
  if (t < D) {
    int c = t;
    float acc = 0.f;
    int run = -1;
    #pragma unroll
    for (int s2 = 0; s2 < 16; ++s2) {
      int g = gbuf[s2];
      if (g < 0) break;
      if (g != run) {
        if (run >= 0) atomicAdd(&P[(size_t)run * D + c], acc);
        run = g;
        acc = 0.f;
      }
      acc += buf[s2][c];
    }
    if (run >= 0) atomicAdd(&P[(size_t)run * D + c], acc);
  }
}

// out[g] = (P[g] @ W2) / cnt(g) + b2 ; cnt via binary search (fused k_cnt2)
__global__ void k_out(const float* __restrict__ P, const int* __restrict__ batch,
                      const void* __restrict__ W2, const void* __restrict__ b2,
                      float* __restrict__ Out, int ng, int nn,
                      const int* __restrict__ flag) {
  int idx = blockIdx.x * blockDim.x + threadIdx.x;
  if (idx >= ng * D) return;
  int g = idx >> 7, c = idx & 127;
  int lo = 0, hi = nn;
  while (lo < hi) { int mid = (lo + hi) >> 1; if (batch[mid] < g) lo = mid + 1; else hi = mid; }
  int s = lo;
  hi = nn;
  while (lo < hi) { int mid = (lo + hi) >> 1; if (batch[mid] < g + 1) lo = mid + 1; else hi = mid; }
  int m = lo - s;
  float inv = (m > 0) ? (1.0f / (float)m) : 0.0f;
  const float* pr = P + (size_t)g * D;
  float acc = 0.f;
  if (flag[3]) {
    const unsigned short* wu = (const unsigned short*)W2;
    for (int k = 0; k < D; ++k) acc += pr[k] * bf2f(wu[k * D + c]);
  } else {
    const float* wf = (const float*)W2;
    for (int k = 0; k < D; ++k) acc += pr[k] * wf[k * D + c];
  }
  acc *= inv;
  if (m > 0) acc += flag[4] ? bf2f(((const unsigned short*)b2)[c]) : ((const float*)b2)[c];
  Out[idx] = acc;
}

extern "C" void kernel_launch(void* const* d_in, const int* in_sizes, int n_in,
                              void* d_out, int out_size, void* d_ws, size_t ws_size,
                              hipStream_t stream) {
  const void* xr = d_in[0];
  const void* eir = d_in[1];
  const void* batchr = d_in[2];
  const void* emb = d_in[3];
  const void* W1 = d_in[4];
  const void* b1 = d_in[5];
  const void* W2 = d_in[6];
  const void* b2 = d_in[7];
  float* out = (float*)d_out;

  const int nn = in_sizes[0];
  const int ne = in_sizes[1] / 2;
  const int vocab = in_sizes[3] / D;
  const int ng = out_size / D;
  const int nb = (nn + 1023) / 1024;
  const int ngD = ng * D;

  char* p = (char*)d_ws;
  auto alloc = [&](size_t bytes) -> char* {
    char* r = p;
    p += (bytes + 511) & ~(size_t)511;
    return r;
  };
  int* flag = (int*)alloc(512);
  int* xs = (int*)alloc((size_t)nn * 4);
  int* batchs = (int*)alloc((size_t)nn * 4);
  int* indeg = (int*)alloc((size_t)nn * 4);
  int* off = (int*)alloc((size_t)nn * 4);
  int* cursor = (int*)alloc((size_t)nn * 4);
  float* dis = (float*)alloc((size_t)nn * 4);
  int* bsum = (int*)alloc((size_t)nb * 4);
  int2* csr = (int2*)alloc((size_t)ne * 8);
  unsigned short* G = (unsigned short*)alloc((size_t)vocab * D * 2);  // fp16
  unsigned short* H1 = (unsigned short*)alloc((size_t)nn * D * 2);
  float* P = (float*)alloc((size_t)ngD * 4);

  // 1. detect dtypes + zero indeg/P (no memsets at all)
  {
    int zb = (nn + ngD + 255) / 256;
    k_prep<<<6 + zb, 256, 0, stream>>>(
        (const unsigned short*)emb, vocab * D,
        (const unsigned short*)W1, D * D,
        (const unsigned short*)b1, D,
        (const unsigned short*)W2, D * D,
        (const unsigned short*)b2, D,
        (const unsigned int*)eir, flag, indeg, P, nn, ngD);
  }

  // 2. x/batch conversion + in-degree count (from raw edge dst),
  //    FUSED with G = emb @ W1 (fp16). No srcs/dsts round-trip.
  {
    long long tot = 2LL * nn + ne;
    int convBlocks = (int)((tot + 255) / 256);
    int gemmBlocks = (vocab * D + 255) / 256;
    k_convi_gemm<<<convBlocks + gemmBlocks, 256, 0, stream>>>(
        xr, eir, batchr, xs, batchs, indeg, nn, ne, vocab, ng,
        flag, emb, W1, G, convBlocks);
  }

  // 3-5. CSR build (fill reads raw edge_index, L3-warm)
  k_scan1<<<nb, 1024, 0, stream>>>(indeg, off, bsum, nn);
  k_scan23<<<nb, 1024, 0, stream>>>(off, cursor, dis, indeg, bsum, nn);
  k_fill<<<(ne + 255) / 256, 256, 0, stream>>>(eir, xs, dis, cursor, csr,
                                               ne, nn, flag + 5);

  // 6. layer 1 aggregate + relu  (16 lanes/node, row double-buffer)
  {
    long long thr = (long long)nn * 16;
    k_aggrelu<<<(int)((thr + 255) / 256), 256, 0, stream>>>(xs, G, b1, off, indeg,
                                                            dis, csr, H1, nn, flag);
  }

  // 7. layer 2 aggregate + pool  (16 lanes/node, row double-buffer)
  k_agg2pool<<<(nn + 15) / 16, 256, 0, stream>>>(H1, off, indeg, dis, csr,
                                                 batchs, P, nn);

  // 8. final small GEMM + mean + bias (cnt fused via binary search)
  k_out<<<(ngD + 255) / 256, 256, 0, stream>>>(P, batchs, W2, b2, out, ng, nn, flag);
}

// Round 11
// 212.271 us; speedup vs baseline: 1.0082x; 1.0082x over previous
//
#include <hip/hip_runtime.h>
#include <hip/hip_bf16.h>
#include <hip/hip_fp16.h>

#define D 128

__device__ __forceinline__ float bf2f(unsigned short u) {
  return __uint_as_float(((unsigned int)u) << 16);
}
__device__ __forceinline__ unsigned short f2bf(float f) {
  unsigned int x = __float_as_uint(f);
  x += 0x7fff + ((x >> 16) & 1);
  return (unsigned short)(x >> 16);
}
__device__ __forceinline__ float h2f(unsigned short b) {
  return __half2float(__ushort_as_half(b));
}
// unpack 2 fp16 packed in a uint
__device__ __forceinline__ float2 up2(unsigned int u) {
  __half2 h = *reinterpret_cast<__half2*>(&u);
  return __half22float2(h);
}
// a[0..7] += w * (8 fp16 packed in uint4)
__device__ __forceinline__ void fma8h(float* a, uint4 v, float w) {
  float2 t;
  t = up2(v.x); a[0] += w * t.x; a[1] += w * t.y;
  t = up2(v.y); a[2] += w * t.x; a[3] += w * t.y;
  t = up2(v.z); a[4] += w * t.x; a[5] += w * t.y;
  t = up2(v.w); a[6] += w * t.x; a[7] += w * t.y;
}
// add 8 bf16 (packed in uint4) into 8 float accumulators
__device__ __forceinline__ void add8(float* a, uint4 v) {
  a[0] += __uint_as_float(v.x << 16);
  a[1] += __uint_as_float(v.x & 0xffff0000u);
  a[2] += __uint_as_float(v.y << 16);
  a[3] += __uint_as_float(v.y & 0xffff0000u);
  a[4] += __uint_as_float(v.z << 16);
  a[5] += __uint_as_float(v.z & 0xffff0000u);
  a[6] += __uint_as_float(v.w << 16);
  a[7] += __uint_as_float(v.w & 0xffff0000u);
}

// flags: [0..4]=float tensor is-bf16 (emb,W1,b1,W2,b2), [5]=ints-int64

// fused: dtype detect (blocks 0..5) + zero indeg (nn ints) + zero P (ngD floats)
__global__ void k_prep(const unsigned short* __restrict__ t0, int n0,
                       const unsigned short* __restrict__ t1, int n1,
                       const unsigned short* __restrict__ t2, int n2,
                       const unsigned short* __restrict__ t3, int n3,
                       const unsigned short* __restrict__ t4, int n4,
                       const unsigned int* __restrict__ ei32,
                       int* __restrict__ flag, int* __restrict__ indeg,
                       float* __restrict__ P, int nn, int ngD) {
  int b = blockIdx.x;
  if (b < 5) {
    const unsigned short* tabs[5] = {t0, t1, t2, t3, t4};
    int ns[5] = {n0, n1, n2, n3, n4};
    const unsigned short* u16 = tabs[b];
    int n = ns[b];
    __shared__ int cnt;
    int K = n / 2 < 256 ? n / 2 : 256;
    if (threadIdx.x == 0) cnt = 0;
    __syncthreads();
    if (threadIdx.x < K) {
      unsigned short u = u16[threadIdx.x * 2];
      int e = (u >> 7) & 0xFF;
      if (u == 0 || (e >= 100 && e <= 140)) atomicAdd(&cnt, 1);
    }
    __syncthreads();
    if (threadIdx.x == 0) flag[b] = (cnt * 2 >= K) ? 1 : 0;
  } else if (b == 5) {
    __shared__ int z;
    if (threadIdx.x == 0) z = 0;
    __syncthreads();
    if (threadIdx.x < 64 && ei32[threadIdx.x * 2 + 1] == 0u) atomicAdd(&z, 1);
    __syncthreads();
    if (threadIdx.x == 0) flag[5] = (z >= 60) ? 1 : 0;
  } else {
    int i = (b - 6) * 256 + threadIdx.x;
    if (i < nn) indeg[i] = 0;
    int j = i - nn;
    if (j >= 0 && j < ngD) P[j] = 0.f;
  }
}

// fused: int conversion (x, batch) + in-degree count from raw edge dst
// (blocks < convBlocks) AND G = emb @ W1 fp16 (remaining blocks).
// srcs/dsts are never materialized — k_fill re-reads edge_index (L3-warm).
__global__ void k_convi_gemm(const void* __restrict__ xr, const void* __restrict__ eir,
                             const void* __restrict__ br,
                             int* __restrict__ xs, int* __restrict__ batchs,
                             int* __restrict__ indeg,
                             int nn, int ne, int vocab, int ng,
                             const int* __restrict__ flag,
                             const void* __restrict__ emb,
                             const void* __restrict__ W1,
                             unsigned short* __restrict__ G,
                             int convBlocks) {
  if (blockIdx.x < convBlocks) {
    long long i = (long long)blockIdx.x * blockDim.x + threadIdx.x;
    int is64 = flag[5];
    if (i < nn) {
      int v = is64 ? (int)((const long long*)xr)[i] : ((const int*)xr)[i];
      v = v < 0 ? 0 : (v > vocab - 1 ? vocab - 1 : v);
      xs[i] = v;
    } else if (i < (long long)nn + ne) {
      long long j = i - nn;
      int v = is64 ? (int)((const long long*)eir)[ne + j] : ((const int*)eir)[ne + j];
      v = v < 0 ? 0 : (v > nn - 1 ? nn - 1 : v);
      atomicAdd(&indeg[v], 1);
    } else if (i < 2LL * nn + ne) {
      long long j = i - nn - ne;
      int v = is64 ? (int)((const long long*)br)[j] : ((const int*)br)[j];
      v = v < 0 ? 0 : (v > ng - 1 ? ng - 1 : v);
      batchs[j] = v;
    }
  } else {
    int idx = (blockIdx.x - convBlocks) * blockDim.x + threadIdx.x;
    if (idx >= vocab * D) return;
    int r = idx >> 7, c = idx & 127;
    int fe = flag[0], fw = flag[1];
    const float* ef = (const float*)emb;
    const unsigned short* eu = (const unsigned short*)emb;
    const float* wf = (const float*)W1;
    const unsigned short* wu = (const unsigned short*)W1;
    size_t ro = (size_t)r * D;
    float acc = 0.f;
    if (fe) {
      if (fw) { for (int k = 0; k < D; ++k) acc += bf2f(eu[ro + k]) * bf2f(wu[k * D + c]); }
      else    { for (int k = 0; k < D; ++k) acc += bf2f(eu[ro + k]) * wf[k * D + c]; }
    } else {
      if (fw) { for (int k = 0; k < D; ++k) acc += ef[ro + k] * bf2f(wu[k * D + c]); }
      else    { for (int k = 0; k < D; ++k) acc += ef[ro + k] * wf[k * D + c]; }
    }
    G[idx] = __half_as_ushort(__float2half_rn(acc));
  }
}

// ---------------- CSR scan -------------------------------------------------
__global__ __launch_bounds__(1024) void k_scan1(const int* __restrict__ indeg,
                                                int* __restrict__ off,
                                                int* __restrict__ bsum, int nn) {
  int t = threadIdx.x;
  int idx = blockIdx.x * 1024 + t;
  int v = (idx < nn) ? indeg[idx] : 0;
  int lane = t & 63, wid = t >> 6;
  int inc = v;
  #pragma unroll
  for (int d = 1; d < 64; d <<= 1) {
    int u = __shfl_up(inc, d);
    if (lane >= d) inc += u;
  }
  __shared__ int ws[16];
  if (lane == 63) ws[wid] = inc;
  __syncthreads();
  if (wid == 0) {
    int wv = (lane < 16) ? ws[lane] : 0;
    #pragma unroll
    for (int d = 1; d < 16; d <<= 1) {
      int u = __shfl_up(wv, d);
      if (lane >= d) wv += u;
    }
    if (lane < 16) ws[lane] = wv;
  }
  __syncthreads();
  int base = wid ? ws[wid - 1] : 0;
  if (idx < nn) off[idx] = base + inc - v;
  if (t == 1023) bsum[blockIdx.x] = ws[15];
}

// fused scan2+scan3: each 1024-block reduces bsum[0..blockIdx-1] itself
__global__ __launch_bounds__(1024) void k_scan23(int* __restrict__ off,
                                                 int* __restrict__ cursor,
                                                 float* __restrict__ dis,
                                                 const int* __restrict__ indeg,
                                                 const int* __restrict__ bsum,
                                                 int nn) {
  int b = blockIdx.x, t = threadIdx.x;
  int v = (t < b) ? bsum[t] : 0;  // nb <= 98 < 1024
  #pragma unroll
  for (int d = 32; d; d >>= 1) v += __shfl_xor(v, d);
  __shared__ int ws[16];
  __shared__ int prefix;
  int lane = t & 63, wid = t >> 6;
  if (lane == 0) ws[wid] = v;
  __syncthreads();
  if (t == 0) {
    int s = 0;
    #pragma unroll
    for (int i = 0; i < 16; ++i) s += ws[i];
    prefix = s;
  }
  __syncthreads();
  int idx = b * 1024 + t;
  if (idx < nn) {
    int o = off[idx] + prefix;
    off[idx] = o;
    cursor[idx] = o;
    dis[idx] = rsqrtf((float)indeg[idx] + 1.0f);  // +1 self-loop
  }
}

// fill unified CSR from RAW edge_index: csr[pp] = { src, x[src]|f16(dis)<<16 }
__global__ void k_fill(const void* __restrict__ eir,
                       const int* __restrict__ xs, const float* __restrict__ dis,
                       int* __restrict__ cursor, int2* __restrict__ csr,
                       int ne, int nn, const int* __restrict__ flag64) {
  int e = blockIdx.x * blockDim.x + threadIdx.x;
  if (e >= ne) return;
  int is64 = *flag64;
  int s, d;
  if (is64) {
    s = (int)((const long long*)eir)[e];
    d = (int)((const long long*)eir)[ne + e];
  } else {
    s = ((const int*)eir)[e];
    d = ((const int*)eir)[ne + e];
  }
  s = s < 0 ? 0 : (s > nn - 1 ? nn - 1 : s);
  d = d < 0 ? 0 : (d > nn - 1 ? nn - 1 : d);
  unsigned short hb = __half_as_ushort(__float2half_rn(dis[s]));
  unsigned int packed = (unsigned int)xs[s] | ((unsigned int)hb << 16);
  int pp = atomicAdd(&cursor[d], 1);
  csr[pp] = make_int2(s, (int)packed);
}

// ---- layer1: H1p[n] = dn * relu(dn*(dn*G[x[n]] + sum dis_s*G[x_s]) + b1) --
// 16 lanes/node, uint4 loads of fp16 G rows (4 rows = 1KB per wave-inst),
// 4-wide unconditional batches (R4/R9 structure — measured best; row
// double-buffer was neutral-to-negative here, R10: G is L2-resident and
// 4 waves/SIMD already hide its ~200cy latency).
__global__ __launch_bounds__(256) void k_aggrelu(const int* __restrict__ x,
                                                 const unsigned short* __restrict__ G,
                                                 const void* __restrict__ b1,
                                                 const int* __restrict__ off,
                                                 const int* __restrict__ indeg,
                                                 const float* __restrict__ dis,
                                                 const int2* __restrict__ csr,
                                                 unsigned short* __restrict__ H1,
                                                 int nn, const int* __restrict__ flag) {
  int gid = blockIdx.x * blockDim.x + threadIdx.x;
  int n = gid >> 4;
  if (n >= nn) return;
  int lane = threadIdx.x & 15;
  float dn = dis[n];
  const uint4* G4 = (const uint4*)G;  // fp16 row = 16 uint4 (256 B)
  float a[8];
  {
    uint4 v = G4[(size_t)x[n] * 16 + lane];
    float2 t;
    t = up2(v.x); a[0] = dn * t.x; a[1] = dn * t.y;
    t = up2(v.y); a[2] = dn * t.x; a[3] = dn * t.y;
    t = up2(v.z); a[4] = dn * t.x; a[5] = dn * t.y;
    t = up2(v.w); a[6] = dn * t.x; a[7] = dn * t.y;
  }
  int s0 = off[n], m = indeg[n];
  int j = 0;
  for (; j + 4 <= m; j += 4) {
    int2 c0 = csr[s0 + j],     c1 = csr[s0 + j + 1];
    int2 c2 = csr[s0 + j + 2], c3 = csr[s0 + j + 3];
    uint4 v0 = G4[(size_t)((unsigned)c0.y & 0xFFFFu) * 16 + lane];
    uint4 v1 = G4[(size_t)((unsigned)c1.y & 0xFFFFu) * 16 + lane];
    uint4 v2 = G4[(size_t)((unsigned)c2.y & 0xFFFFu) * 16 + lane];
    uint4 v3 = G4[(size_t)((unsigned)c3.y & 0xFFFFu) * 16 + lane];
    fma8h(a, v0, h2f((unsigned short)((unsigned)c0.y >> 16)));
    fma8h(a, v1, h2f((unsigned short)((unsigned)c1.y >> 16)));
    fma8h(a, v2, h2f((unsigned short)((unsigned)c2.y >> 16)));
    fma8h(a, v3, h2f((unsigned short)((unsigned)c3.y >> 16)));
  }
  for (; j < m; ++j) {
    int2 c = csr[s0 + j];
    uint4 v = G4[(size_t)((unsigned)c.y & 0xFFFFu) * 16 + lane];
    fma8h(a, v, h2f((unsigned short)((unsigned)c.y >> 16)));
  }
  float bb[8];
  if (flag[2]) {
    uint4 bu = ((const uint4*)b1)[lane];  // 8 bf16
    bb[0] = bf2f((unsigned short)(bu.x & 0xFFFF)); bb[1] = bf2f((unsigned short)(bu.x >> 16));
    bb[2] = bf2f((unsigned short)(bu.y & 0xFFFF)); bb[3] = bf2f((unsigned short)(bu.y >> 16));
    bb[4] = bf2f((unsigned short)(bu.z & 0xFFFF)); bb[5] = bf2f((unsigned short)(bu.z >> 16));
    bb[6] = bf2f((unsigned short)(bu.w & 0xFFFF)); bb[7] = bf2f((unsigned short)(bu.w >> 16));
  } else {
    float4 b0 = ((const float4*)b1)[2 * lane];
    float4 b1v = ((const float4*)b1)[2 * lane + 1];
    bb[0] = b0.x; bb[1] = b0.y; bb[2] = b0.z; bb[3] = b0.w;
    bb[4] = b1v.x; bb[5] = b1v.y; bb[6] = b1v.z; bb[7] = b1v.w;
  }
  ushort4 o0, o1;
  o0.x = f2bf(dn * fmaxf(dn * a[0] + bb[0], 0.f));
  o0.y = f2bf(dn * fmaxf(dn * a[1] + bb[1], 0.f));
  o0.z = f2bf(dn * fmaxf(dn * a[2] + bb[2], 0.f));
  o0.w = f2bf(dn * fmaxf(dn * a[3] + bb[3], 0.f));
  o1.x = f2bf(dn * fmaxf(dn * a[4] + bb[4], 0.f));
  o1.y = f2bf(dn * fmaxf(dn * a[5] + bb[5], 0.f));
  o1.z = f2bf(dn * fmaxf(dn * a[6] + bb[6], 0.f));
  o1.w = f2bf(dn * fmaxf(dn * a[7] + bb[7], 0.f));
  ((ushort4*)(H1 + (size_t)n * D))[2 * lane] = o0;
  ((ushort4*)(H1 + (size_t)n * D))[2 * lane + 1] = o1;
}

// ---- fused layer2 + pool: 16 lanes/node, uint4 (16B) loads; ROW double-
// buffer: chunk k+1's 4 row-loads issued before consuming chunk k, so add8
// VALU overlaps load flight (explicit scalars, no predication).
__global__ __launch_bounds__(256) void k_agg2pool(
    const unsigned short* __restrict__ H1, const int* __restrict__ off,
    const int* __restrict__ indeg, const float* __restrict__ dis,
    const int2* __restrict__ csr, const int* __restrict__ batch,
    float* __restrict__ P, int nn) {
  __shared__ float buf[16][D];
  __shared__ int gbuf[16];
  int t = threadIdx.x;
  int slot = t >> 4, lane = t & 15;
  int n = blockIdx.x * 16 + slot;
  float a[8] = {0.f, 0.f, 0.f, 0.f, 0.f, 0.f, 0.f, 0.f};
  if (n < nn) {
    float dn = dis[n];
    const uint4* H4 = (const uint4*)H1;  // row = 16 uint4
    add8(a, H4[(size_t)n * 16 + lane]);  // self term
    int s0 = off[n], m = indeg[n];
    int j = 0;
    if (m >= 4) {
      int i0 = csr[s0].x, i1 = csr[s0 + 1].x;
      int i2 = csr[s0 + 2].x, i3 = csr[s0 + 3].x;
      uint4 vA = H4[(size_t)i0 * 16 + lane];
      uint4 vB = H4[(size_t)i1 * 16 + lane];
      uint4 vC = H4[(size_t)i2 * 16 + lane];
      uint4 vD = H4[(size_t)i3 * 16 + lane];
      for (; j + 8 <= m; j += 4) {
        int p0 = csr[s0 + j + 4].x, p1 = csr[s0 + j + 5].x;
        int p2 = csr[s0 + j + 6].x, p3 = csr[s0 + j + 7].x;
        uint4 wA = H4[(size_t)p0 * 16 + lane];
        uint4 wB = H4[(size_t)p1 * 16 + lane];
        uint4 wC = H4[(size_t)p2 * 16 + lane];
        uint4 wD = H4[(size_t)p3 * 16 + lane];
        add8(a, vA); add8(a, vB); add8(a, vC); add8(a, vD);
        vA = wA; vB = wB; vC = wC; vD = wD;
      }
      add8(a, vA); add8(a, vB); add8(a, vC); add8(a, vD);
      j += 4;
    }
    for (; j < m; ++j) {
      int e = csr[s0 + j].x;
      add8(a, H4[(size_t)e * 16 + lane]);
    }
    #pragma unroll
    for (int q = 0; q < 8; ++q) a[q] *= dn;
  }
  ((float4*)&buf[slot][lane * 8])[0] = make_float4(a[0], a[1], a[2], a[3]);
  ((float4*)&buf[slot][lane * 8])[1] = make_float4(a[4], a[5], a[6], a[7]);
  if (lane == 0) gbuf[slot] = (n < nn) ? batch[n] : -1;
  __syncthreads();
  if (t < D) {
    int c = t;
    float acc = 0.f;
    int run = -1;
    #pragma unroll
    for (int s2 = 0; s2 < 16; ++s2) {
      int g = gbuf[s2];
      if (g < 0) break;
      if (g != run) {
        if (run >= 0) atomicAdd(&P[(size_t)run * D + c], acc);
        run = g;
        acc = 0.f;
      }
      acc += buf[s2][c];
    }
    if (run >= 0) atomicAdd(&P[(size_t)run * D + c], acc);
  }
}

// out[g] = (P[g] @ W2) / cnt(g) + b2 ; cnt via binary search (fused k_cnt2)
__global__ void k_out(const float* __restrict__ P, const int* __restrict__ batch,
                      const void* __restrict__ W2, const void* __restrict__ b2,
                      float* __restrict__ Out, int ng, int nn,
                      const int* __restrict__ flag) {
  int idx = blockIdx.x * blockDim.x + threadIdx.x;
  if (idx >= ng * D) return;
  int g = idx >> 7, c = idx & 127;
  int lo = 0, hi = nn;
  while (lo < hi) { int mid = (lo + hi) >> 1; if (batch[mid] < g) lo = mid + 1; else hi = mid; }
  int s = lo;
  hi = nn;
  while (lo < hi) { int mid = (lo + hi) >> 1; if (batch[mid] < g + 1) lo = mid + 1; else hi = mid; }
  int m = lo - s;
  float inv = (m > 0) ? (1.0f / (float)m) : 0.0f;
  const float* pr = P + (size_t)g * D;
  float acc = 0.f;
  if (flag[3]) {
    const unsigned short* wu = (const unsigned short*)W2;
    for (int k = 0; k < D; ++k) acc += pr[k] * bf2f(wu[k * D + c]);
  } else {
    const float* wf = (const float*)W2;
    for (int k = 0; k < D; ++k) acc += pr[k] * wf[k * D + c];
  }
  acc *= inv;
  if (m > 0) acc += flag[4] ? bf2f(((const unsigned short*)b2)[c]) : ((const float*)b2)[c];
  Out[idx] = acc;
}

extern "C" void kernel_launch(void* const* d_in, const int* in_sizes, int n_in,
                              void* d_out, int out_size, void* d_ws, size_t ws_size,
                              hipStream_t stream) {
  const void* xr = d_in[0];
  const void* eir = d_in[1];
  const void* batchr = d_in[2];
  const void* emb = d_in[3];
  const void* W1 = d_in[4];
  const void* b1 = d_in[5];
  const void* W2 = d_in[6];
  const void* b2 = d_in[7];
  float* out = (float*)d_out;

  const int nn = in_sizes[0];
  const int ne = in_sizes[1] / 2;
  const int vocab = in_sizes[3] / D;
  const int ng = out_size / D;
  const int nb = (nn + 1023) / 1024;
  const int ngD = ng * D;

  char* p = (char*)d_ws;
  auto alloc = [&](size_t bytes) -> char* {
    char* r = p;
    p += (bytes + 511) & ~(size_t)511;
    return r;
  };
  int* flag = (int*)alloc(512);
  int* xs = (int*)alloc((size_t)nn * 4);
  int* batchs = (int*)alloc((size_t)nn * 4);
  int* indeg = (int*)alloc((size_t)nn * 4);
  int* off = (int*)alloc((size_t)nn * 4);
  int* cursor = (int*)alloc((size_t)nn * 4);
  float* dis = (float*)alloc((size_t)nn * 4);
  int* bsum = (int*)alloc((size_t)nb * 4);
  int2* csr = (int2*)alloc((size_t)ne * 8);
  unsigned short* G = (unsigned short*)alloc((size_t)vocab * D * 2);  // fp16
  unsigned short* H1 = (unsigned short*)alloc((size_t)nn * D * 2);
  float* P = (float*)alloc((size_t)ngD * 4);

  // 1. detect dtypes + zero indeg/P (no memsets at all)
  {
    int zb = (nn + ngD + 255) / 256;
    k_prep<<<6 + zb, 256, 0, stream>>>(
        (const unsigned short*)emb, vocab * D,
        (const unsigned short*)W1, D * D,
        (const unsigned short*)b1, D,
        (const unsigned short*)W2, D * D,
        (const unsigned short*)b2, D,
        (const unsigned int*)eir, flag, indeg, P, nn, ngD);
  }

  // 2. x/batch conversion + in-degree count (from raw edge dst),
  //    FUSED with G = emb @ W1 (fp16). No srcs/dsts round-trip.
  {
    long long tot = 2LL * nn + ne;
    int convBlocks = (int)((tot + 255) / 256);
    int gemmBlocks = (vocab * D + 255) / 256;
    k_convi_gemm<<<convBlocks + gemmBlocks, 256, 0, stream>>>(
        xr, eir, batchr, xs, batchs, indeg, nn, ne, vocab, ng,
        flag, emb, W1, G, convBlocks);
  }

  // 3-5. CSR build (fill reads raw edge_index, L3-warm)
  k_scan1<<<nb, 1024, 0, stream>>>(indeg, off, bsum, nn);
  k_scan23<<<nb, 1024, 0, stream>>>(off, cursor, dis, indeg, bsum, nn);
  k_fill<<<(ne + 255) / 256, 256, 0, stream>>>(eir, xs, dis, cursor, csr,
                                               ne, nn, flag + 5);

  // 6. layer 1 aggregate + relu  (16 lanes/node, 4-wide batches)
  {
    long long thr = (long long)nn * 16;
    k_aggrelu<<<(int)((thr + 255) / 256), 256, 0, stream>>>(xs, G, b1, off, indeg,
                                                            dis, csr, H1, nn, flag);
  }

  // 7. layer 2 aggregate + pool  (16 lanes/node, row double-buffer)
  k_agg2pool<<<(nn + 15) / 16, 256, 0, stream>>>(H1, off, indeg, dis, csr,
                                                 batchs, P, nn);

  // 8. final small GEMM + mean + bias (cnt fused via binary search)
  k_out<<<(ngD + 255) / 256, 256, 0, stream>>>(P, batchs, W2, b2, out, ng, nn, flag);
}